// Round 2
// baseline (66.676 us; speedup 1.0000x reference)
//
#include <hip/hip_runtime.h>
#include <math.h>

#define N_RAYS 131072
#define N_PTS  128
#define FAR_DELTA 1e10f

// DPP cross-lane move: result[lane] = valid(src lane) ? src[srclane] : old[lane].
// CTRL: row_shl:N = 0x100|N (lane i <- lane i+N), row_shr:N = 0x110|N (lane i <- lane i-N).
// DPP rows are 16 lanes — exactly one ray group, so shifts never cross rays.
template<int CTRL>
__device__ __forceinline__ float dpp_mov(float src, float old) {
    return __builtin_bit_cast(float, __builtin_amdgcn_update_dpp(
        __builtin_bit_cast(int, old), __builtin_bit_cast(int, src),
        CTRL, 0xF, 0xF, false));
}

// 16 lanes per ray, 8 consecutive samples per lane, 4 rays per wave, 16 rays per block.
__global__ __launch_bounds__(256, 4) void volrender_kernel(
    const float* __restrict__ density,
    const float* __restrict__ feature,
    const float* __restrict__ depthv,
    float* __restrict__ out)
{
    const int tid = threadIdx.x;
    const int sub = tid & 15;                     // lane position within ray
    const int ray = blockIdx.x * 16 + (tid >> 4); // 16 rays per 256-thread block

    const size_t sbase = (size_t)ray * N_PTS + sub * 8;

    // Coalesced float4 loads: whole wave reads contiguous 2 KiB per instr pair.
    const float4 d0 = *reinterpret_cast<const float4*>(depthv + sbase);
    const float4 d1 = *reinterpret_cast<const float4*>(depthv + sbase + 4);
    const float4 g0 = *reinterpret_cast<const float4*>(density + sbase);
    const float4 g1 = *reinterpret_cast<const float4*>(density + sbase + 4);

    // 24 contiguous feature floats per lane (96 B), 6x dwordx4.
    const float* fb = feature + (size_t)ray * (N_PTS * 3) + sub * 24;
    float ff[24];
    #pragma unroll
    for (int k = 0; k < 6; ++k)
        *reinterpret_cast<float4*>(&ff[4 * k]) =
            *reinterpret_cast<const float4*>(fb + 4 * k);

    const float dv[8] = {d0.x, d0.y, d0.z, d0.w, d1.x, d1.y, d1.z, d1.w};
    const float sg[8] = {g0.x, g0.y, g0.z, g0.w, g1.x, g1.y, g1.z, g1.w};

    // deltas: within-lane diffs + first depth of the next lane (row_shl:1).
    const float dn = dpp_mov<0x101>(d0.x, 0.0f);
    float dl[8];
    #pragma unroll
    for (int j = 0; j < 7; ++j) dl[j] = dv[j + 1] - dv[j];
    dl[7] = (sub == 15) ? FAR_DELTA : (dn - dv[7]);

    // t_j = exp(-sigma_j * delta_j); in-lane inclusive products p_j.
    float t[8], p[8];
    #pragma unroll
    for (int j = 0; j < 8; ++j) t[j] = __expf(-sg[j] * dl[j]);
    p[0] = t[0];
    #pragma unroll
    for (int j = 1; j < 8; ++j) p[j] = p[j - 1] * t[j];

    // Cross-lane inclusive product scan of per-lane product (Kogge-Stone, row_shr).
    float scan = p[7];
    scan *= dpp_mov<0x111>(scan, 1.0f);
    scan *= dpp_mov<0x112>(scan, 1.0f);
    scan *= dpp_mov<0x114>(scan, 1.0f);
    scan *= dpp_mov<0x118>(scan, 1.0f);
    // Exclusive prefix: transmittance T at this lane's first sample.
    const float excl = dpp_mov<0x111>(scan, 1.0f);

    // Per-sample T, weights, feature/depth partials.
    float fx = 0.f, fy = 0.f, fz = 0.f, st = 0.f, sd = 0.f;
    #pragma unroll
    for (int j = 0; j < 8; ++j) {
        const float T = (j == 0) ? excl : excl * p[j - 1];
        const float w = fmaf(-T, t[j], T);        // T*(1-t)
        fx = fmaf(w, ff[3 * j + 0], fx);
        fy = fmaf(w, ff[3 * j + 1], fy);
        fz = fmaf(w, ff[3 * j + 2], fz);
        const float ts = (T < 1.0f) ? t[j] : 0.0f;
        st += ts;
        sd = fmaf(ts, dv[j], sd);
    }

    // Cross-lane sum reductions to lane sub==0 (row_shl tree, 0-fill identity).
    #define RED16(x)                 \
        x += dpp_mov<0x108>(x, 0.f); \
        x += dpp_mov<0x104>(x, 0.f); \
        x += dpp_mov<0x102>(x, 0.f); \
        x += dpp_mov<0x101>(x, 0.f);
    RED16(fx) RED16(fy) RED16(fz) RED16(st) RED16(sd)
    #undef RED16

    if (sub == 0) {
        out[(size_t)ray * 3 + 0] = fx;
        out[(size_t)ray * 3 + 1] = fy;
        out[(size_t)ray * 3 + 2] = fz;
        const float dep = sd / st;
        out[(size_t)N_RAYS * 3 + ray] = (dep == 0.0f) ? INFINITY : dep;
    }
}

extern "C" void kernel_launch(void* const* d_in, const int* in_sizes, int n_in,
                              void* d_out, int out_size, void* d_ws, size_t ws_size,
                              hipStream_t stream) {
    const float* density = (const float*)d_in[0];
    const float* feature = (const float*)d_in[1];
    const float* depthv  = (const float*)d_in[2];
    float* out = (float*)d_out;

    const int grid = N_RAYS / 16;   // 16 rays per 256-thread block
    volrender_kernel<<<grid, 256, 0, stream>>>(density, feature, depthv, out);
}